// Round 10
// baseline (54.061 us; speedup 1.0000x reference)
//
#include <hip/hip_runtime.h>
#include <math.h>

// ---------------------------------------------------------------------------
// CNN_88098369175791 — R10: R9 structure + batched weight prefetch (warm L2
// in P0, latency paid once & overlapped) + halved serial matvec chains
// (z / w~ / wv split into e-halves; consumers sum the halves).
// ---------------------------------------------------------------------------

#define NWG 8
#define NT  1024

constexpr int WLEN = 140;
constexpr int TDN  = 14;
constexpr int NOFC = 119;

// d_ws: [0,64) bar0 | [64,128) bar1 | +128 acc[2] | +192 done | +512 G arena
constexpr int G_V16 = 0;    // [32] floats (at d_ws+512)
constexpr int G_DD  = 64;   // [238]

// ---------------- LDS arena (floats) ---------------------------------------
constexpr int EEG = 0;      // [16][119]
constexpr int WA  = 1904;   // 140
constexpr int WB  = 2044;   // 140
constexpr int LNT = 2184;   // [119][16]
constexpr int QP4 = 4088;   // [4][119]
constexpr int Z8  = 4564;   // [2][4][119] z halves
constexpr int UD  = 5516;   // [119]
constexpr int WT2 = 5636;   // [2][119] w~ halves
constexpr int WV2 = 5876;   // [2][119] wv halves
constexpr int VT  = 6114;   // [14]
constexpr int SC4 = 6128;   // [4][14]
constexpr int BKQ = 6184;   // [4]
constexpr int CVB = 6188, CBO = 6189;
constexpr int WQH = 6192;   // [16]
constexpr int WKL = 6208;   // [16]
constexpr int WVL = 6224;   // [16]
constexpr int WQT = 6240;   // [16]
constexpr int CST = 6256;   // [1]
constexpr int AC  = 6260;   // [16]
constexpr int BC  = 6276;   // [16]
constexpr int G1L = 6292;   // [30]
constexpr int MXT = 6324;   // [512] max_fc_w transposed [c][16]
constexpr int MXB = 6836;   // [16]
constexpr int KPH = 6852;   // [119][16]
constexpr int VPS = 8756;   // [119][20] (16B-aligned, padded)
constexpr int S1H = 11136;  // [119]
constexpr int S2H = 11255;  // [119]
constexpr int OWS = 11376;  // [256] out_w[mh] transposed [e][c]
constexpr int OBS = 11632;  // [16]
constexpr int O1W = 11648;  // [15][240] my out1_w rows
constexpr int O1B = 15248;  // [15]
constexpr int O2WS= 15264;  // [30]
constexpr int O2B = 15294;  // [2]
constexpr int FCW = 15296;  // [2]
constexpr int FCB = 15298;  // [2]
constexpr int DDL = 15300;  // [238]
constexpr int HHL = 15538;  // [15]
constexpr int VSL = 15554;  // [32]
constexpr int ARENA = 15586; // 62,344 B

struct Args {
  const float *x, *td_in_w, *td_in_b, *td_out_w, *td_out_b;
  const float *cm_in_w, *cm_in_b, *cm_out_w, *cm_out_b;
  const float *mc_w, *mc_b, *max_fc_w, *max_fc_b, *proj_w;
  const float *ln_g, *ln_b, *fc_w, *fc_b;
  const float *out1_w, *out1_b, *out2_w, *out2_b;
  float *out;
  unsigned int *bar;   // d_ws base
  float *G;            // d_ws + 512
};

__device__ __forceinline__ float sigmf(float v) {
  return 1.0f / (1.0f + __expf(-v));
}

__device__ __forceinline__ void gbar(unsigned int* p) {
  __syncthreads();
  if (threadIdx.x == 0) {
    __hip_atomic_fetch_add(p, 1u, __ATOMIC_ACQ_REL, __HIP_MEMORY_SCOPE_AGENT);
    while (__hip_atomic_load(p, __ATOMIC_RELAXED, __HIP_MEMORY_SCOPE_AGENT) < (unsigned)NWG) {
      __builtin_amdgcn_s_sleep(1);
    }
    __builtin_amdgcn_fence(__ATOMIC_ACQUIRE, "agent");
  }
  __syncthreads();
}

__device__ __forceinline__ float dot119(const float* __restrict__ w,
                                        const float* __restrict__ x,
                                        int lane16) {
  float a0 = 0.f, a1 = 0.f;
#pragma unroll
  for (int t = 0; t < 7; ++t) {
    float wv = w[lane16 + 16 * t];
    float xv = x[lane16 + 16 * t];
    if (t & 1) a1 += wv * xv; else a0 += wv * xv;
  }
  if (lane16 < 7) a0 += w[112 + lane16] * x[112 + lane16];
  float acc = a0 + a1;
#pragma unroll
  for (int m = 1; m < 16; m <<= 1) acc += __shfl_xor(acc, m);
  return acc;
}

__device__ __forceinline__ float dot16f4(const float* __restrict__ x,
                                         const float* __restrict__ w) {
  const float4* xa = (const float4*)x; const float4* wa = (const float4*)w;
  float4 x0 = xa[0], x1 = xa[1], x2 = xa[2], x3 = xa[3];
  float4 w0 = wa[0], w1 = wa[1], w2 = wa[2], w3 = wa[3];
  float d0 = x0.x*w0.x + x0.y*w0.y + x0.z*w0.z + x0.w*w0.w;
  float d1 = x1.x*w1.x + x1.y*w1.y + x1.z*w1.z + x1.w*w1.w;
  float d2 = x2.x*w2.x + x2.y*w2.y + x2.z*w2.z + x2.w*w2.w;
  float d3 = x3.x*w3.x + x3.y*w3.y + x3.z*w3.z + x3.w*w3.w;
  return (d0 + d1) + (d2 + d3);
}

__global__ __launch_bounds__(NT) void fused_cnn_kernel(Args a) {
  __shared__ __align__(16) float S[ARENA];
  const int tid = threadIdx.x;
  const int wgid = blockIdx.x;
  const int grp = tid >> 4;
  const int lane16 = tid & 15;
  float* G = a.G;

  const int s  = wgid >> 2;              // 0: A-stream (m0), 1: B-stream (m3)
  const int i0 = (wgid & 3) * 4;         // v16 slots
  const int mh = s ? 3 : 0;              // heavy cm-MHA
  const int lm = s ? 2 : 1;              // folded light cm-MHA
  const int q4 = wgid & 3;
  const int r0 = q4 * 30;
  const int nr = (q4 == 3) ? 29 : 30;
  const int wavX = s ? WB : WA;

  // ---- P0: stage x + static prefetches + L2 warm-read of all weights ---
  for (int t = tid; t < 16 * NOFC; t += NT) {
    int c = t / NOFC, tt = t - c * NOFC;
    S[EEG + t] = a.x[(1 + c) * WLEN + (WLEN - NOFC) + tt];
  }
  if (tid < WLEN) {
    S[WA + tid] = a.x[tid];
    S[WB + tid] = a.x[17 * WLEN + tid];
  }
  if (tid < 512) {                       // max_fc_w transposed [c][16]
    int t16 = tid >> 5, c32 = tid & 31;
    S[MXT + c32 * 16 + t16] = a.max_fc_w[tid];
  }
  if (tid < 16)  S[MXB + tid] = a.max_fc_b[tid];
  if (tid < 256) {                       // heavy out_w transposed [e][c]
    int c = tid >> 4, e = tid & 15;
    S[OWS + e * 16 + c] = a.cm_out_w[mh * 256 + tid];
  }
  if (tid < 16)  S[OBS + tid] = a.cm_out_b[mh * 16 + tid];
  for (int idx = tid; idx < 15 * 238; idx += NT) {    // my out1_w rows
    int rl = idx / 238, c = idx - rl * 238;
    int r = wgid * 15 + rl;
    S[O1W + rl * 240 + c] = (r < NOFC) ? a.out1_w[r * 238 + c] : 0.0f;
  }
  if (tid < 15) {
    int r = wgid * 15 + tid;
    S[O1B + tid] = (r < NOFC) ? a.out1_b[r] : 0.0f;
  }
  if (tid < 30) {
    int o = tid / 15, j = tid - o * 15;
    int r = wgid * 15 + j;
    S[O2WS + tid] = (r < NOFC) ? a.out2_w[o * NOFC + r] : 0.0f;
  }
  if (tid < 2) {
    S[O2B + tid] = a.out2_b[tid];
    S[FCW + tid] = a.fc_w[tid];
    S[FCB + tid] = a.fc_b[tid];
  }
  // L2 warm-read: pay all weight HBM latency here, in one parallel burst.
  {
    float pf = 0.f;
    for (int i = tid; i < 3 * NOFC * NOFC; i += NT) pf += a.td_in_w[i];
    for (int i = tid; i < NOFC * NOFC; i += NT) pf += a.td_out_w[i];
    for (int i = tid; i < 4 * 48 * 16; i += NT) pf += a.cm_in_w[i];
    asm volatile("" :: "v"(pf));   // keep loads alive (no DCE)
  }
  __syncthreads();

  // ---- A: qp (4 rows, weight-row reuse) + u ----------------------------
  for (int e = grp; e < NOFC; e += 64) {
    const float* wrow = a.td_in_w + e * NOFC;
    float w0 = wrow[lane16], w1 = wrow[lane16 + 16], w2 = wrow[lane16 + 32],
          w3 = wrow[lane16 + 48], w4 = wrow[lane16 + 64], w5 = wrow[lane16 + 80],
          w6 = wrow[lane16 + 96];
    float wt7 = (lane16 < 7) ? wrow[112 + lane16] : 0.0f;
    float b = a.td_in_b[e];
#pragma unroll
    for (int kk = 0; kk < 4; ++kk) {
      const float* x = S + EEG + (i0 + kk) * NOFC;
      float acc = w0 * x[lane16] + w1 * x[lane16 + 16] + w2 * x[lane16 + 32]
                + w3 * x[lane16 + 48] + w4 * x[lane16 + 64] + w5 * x[lane16 + 80]
                + w6 * x[lane16 + 96];
      if (lane16 < 7) acc += wt7 * x[112 + lane16];
#pragma unroll
      for (int mm = 1; mm < 16; mm <<= 1) acc += __shfl_xor(acc, mm);
      if (lane16 == 0) S[QP4 + kk * NOFC + e] = acc + b;
    }
  }
  if (grp >= 55) {                        // u[d] = mc_w[s] . eeg[:,d]
    int d = (grp - 55) * 16 + lane16;
    if (d < NOFC) {
      float acc = 0.f;
#pragma unroll
      for (int i = 0; i < 16; ++i) acc += a.mc_w[s * 16 + i] * S[EEG + i * NOFC + d];
      S[UD + d] = acc;
    }
  }
  __syncthreads();

  // ---- B: z halves | w~ halves | LNT | bkq | we-vectors ----------------
  if (tid < 238) {                        // z_k[t] e-halves (L2-warm cols)
    int half = tid / NOFC, t = tid - half * NOFC;
    int e0 = half * 60, e1 = half ? NOFC : 60;
    float a0 = 0.f, a1 = 0.f, a2 = 0.f, a3 = 0.f;
    const float* base = a.td_in_w + NOFC * NOFC + t;
    for (int e = e0; e < e1; ++e) {
      float w = base[e * NOFC];
      a0 += S[QP4 + e] * w;
      a1 += S[QP4 + NOFC + e] * w;
      a2 += S[QP4 + 2 * NOFC + e] * w;
      a3 += S[QP4 + 3 * NOFC + e] * w;
    }
    S[Z8 + (half * 4 + 0) * NOFC + t] = a0;
    S[Z8 + (half * 4 + 1) * NOFC + t] = a1;
    S[Z8 + (half * 4 + 2) * NOFC + t] = a2;
    S[Z8 + (half * 4 + 3) * NOFC + t] = a3;
  } else if (tid >= 238 && tid < 476) {   // w~ halves
    int i = tid - 238, half = i / NOFC, t = i - half * NOFC;
    int d0 = half * 60, d1 = half ? NOFC : 60;
    float acc = 0.f;
    const float* base = a.td_out_w + t;
    for (int d = d0; d < d1; ++d) acc += S[UD + d] * base[d * NOFC];
    S[WT2 + half * NOFC + t] = acc;
  } else if (tid >= 476 && tid < 476 + NOFC) {   // LNT column
    int t = tid - 476;
    float xv[16]; float mu = 0.f;
#pragma unroll
    for (int c = 0; c < 16; ++c) { xv[c] = S[EEG + c * NOFC + t]; mu += xv[c]; }
    mu *= (1.0f / 16.0f);
    float var = 0.f;
#pragma unroll
    for (int c = 0; c < 16; ++c) { float d = xv[c] - mu; var += d * d; }
    var *= (1.0f / 16.0f);
    float inv = 1.0f / sqrtf(var + 1e-5f);
#pragma unroll
    for (int c = 0; c < 16; ++c)
      S[LNT + t * 16 + c] = (xv[c] - mu) * inv * a.ln_g[c] + a.ln_b[c];
  } else if (tid >= 608 && tid < 672) {          // bkq
    int kk = (tid - 608) >> 4;
    float acc = dot119(S + QP4 + kk * NOFC, a.td_in_b + NOFC, lane16);
    if (lane16 == 0) S[BKQ + kk] = acc;
  } else if (tid >= 672 && tid < 688) {          // weQ heavy
    int e = tid - 672;
    float acc = 0.f;
#pragma unroll
    for (int c = 0; c < 16; ++c) acc += a.proj_w[s * 16 + c] * a.cm_in_w[(mh * 48 + e) * 16 + c];
    S[WQH + e] = acc;
  } else if (tid >= 688 && tid < 704) {          // weK light
    int e = tid - 688;
    float acc = 0.f;
#pragma unroll
    for (int c = 0; c < 16; ++c) acc += a.proj_w[s * 16 + c] * a.cm_in_w[(lm * 48 + 16 + e) * 16 + c];
    S[WKL + e] = acc;
  } else if (tid >= 704 && tid < 720) {          // weV light
    int e = tid - 704;
    float acc = 0.f;
#pragma unroll
    for (int c = 0; c < 16; ++c) acc += a.proj_w[s * 16 + c] * a.cm_in_w[(lm * 48 + 32 + e) * 16 + c];
    S[WVL + e] = acc;
  }
  __syncthreads();

  // ---- C: wv halves | kp/vp staging | td scores ------------------------
  if (tid < 238) {                        // wv[t] = (wt0+wt1) . Wv[:,t]
    int half = tid / NOFC, t = tid - half * NOFC;
    int e0 = half * 60, e1 = half ? NOFC : 60;
    float acc = 0.f;
    const float* base = a.td_in_w + 2 * NOFC * NOFC + t;
    for (int e = e0; e < e1; ++e)
      acc += (S[WT2 + e] + S[WT2 + NOFC + e]) * base[e * NOFC];
    S[WV2 + half * NOFC + t] = acc;
  } else if (tid >= 256 && tid < 688) {   // kp/vp for mh (432 threads, 9 rds)
    for (int o = tid - 256; o < 3808; o += 432) {
      if (o < 1904) {
        int u = o >> 4, e = o & 15;
        S[KPH + o] = dot16f4(S + LNT + u * 16, a.cm_in_w + (mh * 48 + 16 + e) * 16)
                     + a.cm_in_b[mh * 48 + 16 + e];
      } else {
        int o2 = o - 1904, u = o2 >> 4, e = o2 & 15;
        S[VPS + u * 20 + e] = dot16f4(S + LNT + u * 16, a.cm_in_w + (mh * 48 + 32 + e) * 16)
                              + a.cm_in_b[mh * 48 + 32 + e];
      }
    }
  }
  if (grp >= 44) {                        // scores, 3 rounds, z = half0+half1
#pragma unroll
    for (int rnd = 0; rnd < 3; ++rnd) {
      int idx = (grp - 44) + rnd * 20;
      if (idx < 56) {
        int kk = idx / TDN, j = idx - kk * TDN;
        float acc = dot119(S + wavX + j, S + Z8 + kk * NOFC, lane16)
                  + dot119(S + wavX + j, S + Z8 + (4 + kk) * NOFC, lane16);
        if (lane16 == 0)
          S[SC4 + kk * TDN + j] = 0.09166984970282113f * (acc + S[BKQ + kk]);
      }
    }
  }
  __syncthreads();

  // ---- D: vtil | softmax | cvb/cbo | wq~/cst/A1/B1 | s1/s2 -------------
  if (grp < TDN) {                        // vtil = win . (wv0+wv1)
    float acc = dot119(S + wavX + grp, S + WV2, lane16)
              + dot119(S + wavX + grp, S + WV2 + NOFC, lane16);
    if (lane16 == 0) S[VT + grp] = acc;
  } else if (tid >= 224 && tid < 228) {   // softmax
    int k = tid - 224;
    float* r = S + SC4 + k * TDN;
    float mx = r[0];
#pragma unroll
    for (int j = 1; j < TDN; ++j) mx = fmaxf(mx, r[j]);
    float sum = 0.f;
#pragma unroll
    for (int j = 0; j < TDN; ++j) { float p = __expf(r[j] - mx); r[j] = p; sum += p; }
    float inv = 1.0f / sum;
#pragma unroll
    for (int j = 0; j < TDN; ++j) r[j] *= inv;
  } else if (grp == 15) {                 // cvb = bv . (wt0+wt1)
    float acc = dot119(a.td_in_b + 2 * NOFC, S + WT2, lane16)
              + dot119(a.td_in_b + 2 * NOFC, S + WT2 + NOFC, lane16);
    if (lane16 == 0) S[CVB] = acc;
  } else if (grp == 16) {                 // cbo = u . out_b
    float acc = dot119(S + UD, a.td_out_b, lane16);
    if (lane16 == 0) S[CBO] = acc;
  } else if (tid >= 288 && tid < 304) {   // wq~[c]
    int c = tid - 288;
    float acc = 0.f;
#pragma unroll
    for (int e = 0; e < 16; ++e) acc += a.cm_in_w[(lm * 48 + e) * 16 + c] * S[WKL + e];
    S[WQT + c] = acc;
  } else if (tid == 304) {                // cst
    float acc = 0.f;
#pragma unroll
    for (int e = 0; e < 16; ++e) acc += a.cm_in_b[lm * 48 + e] * S[WKL + e];
    S[CST] = acc;
  } else if (tid >= 320 && tid < 336) {   // A1[c]
    int c = tid - 320;
    float acc = 0.f;
#pragma unroll
    for (int e = 0; e < 16; ++e) acc += a.cm_out_w[lm * 256 + c * 16 + e] * S[WVL + e];
    S[AC + c] = acc;
  } else if (tid >= 336 && tid < 352) {   // B1[c]
    int c = tid - 336;
    float acc = 0.f;
#pragma unroll
    for (int e = 0; e < 16; ++e) acc += a.cm_out_w[lm * 256 + c * 16 + e] * a.cm_in_b[lm * 48 + 32 + e];
    S[BC + c] = acc + a.cm_out_b[lm * 16 + c];
  }
  if (tid >= 512 && tid < 750) {          // s1/s2
    int idx = tid - 512;
    int u = (idx < NOFC) ? idx : idx - NOFC;
    const float* kpr = S + KPH + u * 16;
    float acc = 0.f;
    if (idx < NOFC) {
#pragma unroll
      for (int e = 0; e < 16; ++e) acc += S[WQH + e] * kpr[e];
      S[S1H + u] = acc;
    } else {
#pragma unroll
      for (int e = 0; e < 16; ++e) acc += a.cm_in_b[mh * 48 + e] * kpr[e];
      S[S2H + u] = acc;
    }
  }
  __syncthreads();

  // ---- E: v16 -> G | g1 -------------------------------------------------
  if (tid < 4) {
    float acc = 0.f;
#pragma unroll
    for (int j = 0; j < TDN; ++j) acc += S[SC4 + tid * TDN + j] * S[VT + j];
    float v = acc + S[CVB] + S[CBO] + a.mc_b[s];
    G[G_V16 + s * 16 + i0 + tid] = fmaxf(v, 0.f);
  } else if (tid >= 32 && tid < 62) {
    int rl = tid - 32;
    if (rl < nr) {
      int t = r0 + rl;
      float acc = S[CST];
#pragma unroll
      for (int c = 0; c < 16; ++c) acc += S[LNT + t * 16 + c] * S[WQT + c];
      S[G1L + rl] = acc;
    }
  }
  gbar(a.bar + 0);

  // ---- argmax (register, replicated) ------------------------------------
  if (tid < 32) S[VSL + tid] = G[G_V16 + tid];
  __syncthreads();
  int mi;
  {
    float wl = S[MXB + lane16];
#pragma unroll
    for (int c = 0; c < 32; ++c) wl += S[MXT + c * 16 + lane16] * S[VSL + c];
    wl = fmaxf(wl, 0.f);
    float mx = wl;
#pragma unroll
    for (int d = 1; d < 16; d <<= 1) mx = fmaxf(mx, __shfl_xor(mx, d));
    int cand = (wl == mx) ? lane16 : 99;
#pragma unroll
    for (int d = 1; d < 16; d <<= 1) cand = min(cand, __shfl_xor(cand, d));
    mi = min(cand, TDN - 1);
  }

  // ---- attention rows -> G_DD -------------------------------------------
  if (grp < nr) {
    const int t = r0 + grp;
    const float wselq = S[wavX + t + mi];
    float p[8];
    float sum = 0.f;
#pragma unroll
    for (int cc = 0; cc < 8; ++cc) {
      int u = lane16 + cc * 16;
      float e1 = 0.f;
      if (u < NOFC)
        e1 = __expf(0.25f * (wselq * S[S1H + u] + S[S2H + u]));
      p[cc] = e1;
      sum += e1;
    }
#pragma unroll
    for (int d = 1; d < 16; d <<= 1) sum += __shfl_xor(sum, d);
    float inv = 1.0f / sum;

    float oa[16];
#pragma unroll
    for (int e = 0; e < 16; ++e) oa[e] = 0.f;
#pragma unroll
    for (int cc = 0; cc < 8; ++cc) {
      int u = lane16 + cc * 16;
      if (u < NOFC) {
        const float4* v4 = (const float4*)(S + VPS + u * 20);
        float4 v0 = v4[0], v1 = v4[1], v2 = v4[2], v3 = v4[3];
        float pv = p[cc];
        oa[0] += pv*v0.x; oa[1] += pv*v0.y; oa[2] += pv*v0.z; oa[3] += pv*v0.w;
        oa[4] += pv*v1.x; oa[5] += pv*v1.y; oa[6] += pv*v1.z; oa[7] += pv*v1.w;
        oa[8] += pv*v2.x; oa[9] += pv*v2.y; oa[10] += pv*v2.z; oa[11] += pv*v2.w;
        oa[12] += pv*v3.x; oa[13] += pv*v3.y; oa[14] += pv*v3.z; oa[15] += pv*v3.w;
      }
    }
#pragma unroll
    for (int e = 0; e < 16; ++e) {
#pragma unroll
      for (int d = 1; d < 16; d <<= 1) oa[e] += __shfl_xor(oa[e], d);
    }
    float oc = S[OBS + lane16];
#pragma unroll
    for (int e = 0; e < 16; ++e) oc += oa[e] * inv * S[OWS + e * 16 + lane16];
    float dA = oc * S[AC + lane16];
    float dB = oc * S[BC + lane16];
#pragma unroll
    for (int d = 1; d < 16; d <<= 1) {
      dA += __shfl_xor(dA, d);
      dB += __shfl_xor(dB, d);
    }
    const float g = S[G1L + grp];
    float s0 = 0.f, s1a = 0.f;
#pragma unroll
    for (int cc = 0; cc < 8; ++cc) {
      int u = lane16 + cc * 16;
      if (u < NOFC) {
        float w = S[wavX + u + mi];
        float e1 = __expf(0.25f * g * w);
        s0 += e1; s1a += e1 * w;
      }
    }
#pragma unroll
    for (int d = 1; d < 16; d <<= 1) {
      s0 += __shfl_xor(s0, d);
      s1a += __shfl_xor(s1a, d);
    }
    float h = s1a / s0;
    float dval = h * dA + dB;
    if (lane16 == 0)
      G[G_DD + s * NOFC + t] = sigmf(S[FCW + s] * dval + S[FCB + s]);
  }
  gbar(a.bar + 16);

  // ---- head: dd -> LDS, 15 out1 rows, out2 via 2 atomics ----------------
  if (tid < 238) S[DDL + tid] = G[G_DD + tid];
  __syncthreads();
  if (grp < 15) {
    int r = wgid * 15 + grp;
    float acc = 0.f;
#pragma unroll
    for (int k = 0; k < 15; ++k) {
      int c = lane16 + 16 * k;
      if (c < 238) acc += S[O1W + grp * 240 + c] * S[DDL + c];
    }
#pragma unroll
    for (int d = 1; d < 16; d <<= 1) acc += __shfl_xor(acc, d);
    if (lane16 == 0)
      S[HHL + grp] = (r < NOFC) ? sigmf(acc + S[O1B + grp]) : 0.0f;
  }
  __syncthreads();
  if (tid == 0) {
    float p0 = 0.f, p1 = 0.f;
#pragma unroll
    for (int j = 0; j < 15; ++j) {
      p0 += S[O2WS + j] * S[HHL + j];
      p1 += S[O2WS + 15 + j] * S[HHL + j];
    }
    float* acc = (float*)((char*)a.bar + 128);
    unsigned int* done = (unsigned int*)((char*)a.bar + 192);
    __hip_atomic_fetch_add(acc + 0, p0, __ATOMIC_RELAXED, __HIP_MEMORY_SCOPE_AGENT);
    __hip_atomic_fetch_add(acc + 1, p1, __ATOMIC_RELAXED, __HIP_MEMORY_SCOPE_AGENT);
    unsigned old = __hip_atomic_fetch_add(done, 1u, __ATOMIC_ACQ_REL, __HIP_MEMORY_SCOPE_AGENT);
    if (old == NWG - 1) {
      __builtin_amdgcn_fence(__ATOMIC_ACQUIRE, "agent");
      float a0 = __hip_atomic_load(acc + 0, __ATOMIC_RELAXED, __HIP_MEMORY_SCOPE_AGENT);
      float a1 = __hip_atomic_load(acc + 1, __ATOMIC_RELAXED, __HIP_MEMORY_SCOPE_AGENT);
      a.out[0] = sigmf(a0 + S[O2B + 0]);
      a.out[1] = sigmf(a1 + S[O2B + 1]);
    }
  }
}

extern "C" void kernel_launch(void* const* d_in, const int* in_sizes, int n_in,
                              void* d_out, int out_size, void* d_ws, size_t ws_size,
                              hipStream_t stream) {
  Args a;
  a.x        = (const float*)d_in[0];
  a.td_in_w  = (const float*)d_in[1];
  a.td_in_b  = (const float*)d_in[2];
  a.td_out_w = (const float*)d_in[3];
  a.td_out_b = (const float*)d_in[4];
  a.cm_in_w  = (const float*)d_in[5];
  a.cm_in_b  = (const float*)d_in[6];
  a.cm_out_w = (const float*)d_in[7];
  a.cm_out_b = (const float*)d_in[8];
  a.mc_w     = (const float*)d_in[9];
  a.mc_b     = (const float*)d_in[10];
  a.max_fc_w = (const float*)d_in[11];
  a.max_fc_b = (const float*)d_in[12];
  a.proj_w   = (const float*)d_in[13];
  a.ln_g     = (const float*)d_in[14];
  a.ln_b     = (const float*)d_in[15];
  a.fc_w     = (const float*)d_in[16];
  a.fc_b     = (const float*)d_in[17];
  a.out1_w   = (const float*)d_in[18];
  a.out1_b   = (const float*)d_in[19];
  a.out2_w   = (const float*)d_in[20];
  a.out2_b   = (const float*)d_in[21];
  a.out      = (float*)d_out;
  a.bar      = (unsigned int*)d_ws;
  a.G        = (float*)((char*)d_ws + 512);

  // zero barriers + out2 accumulators + done counter each call.
  hipMemsetAsync(d_ws, 0, 512, stream);
  fused_cnn_kernel<<<dim3(NWG), dim3(NT), 0, stream>>>(a);
}

// Round 11
// 33.529 us; speedup vs baseline: 1.6124x; 1.6124x over previous
//
#include <hip/hip_runtime.h>
#include <math.h>

// ---------------------------------------------------------------------------
// CNN_88098369175791 — R11: R9 structure (proven 35.2us) + kp-elimination:
//   s1[u] = wk2.LNT[u] + cqk,  s2[u] = c2k.LNT[u] + cbk
// (wk2 = Wk^T weQ, c2k = Wk^T bq are 16x16 contractions) — the [119][16] kp
// staging (30K MACs + 7.6KB LDS) is never materialized. No other changes.
// ---------------------------------------------------------------------------

#define NWG 8
#define NT  1024

constexpr int WLEN = 140;
constexpr int TDN  = 14;
constexpr int NOFC = 119;

// d_ws: [0,64) bar0 | [64,128) bar1 | +128 acc[2] | +192 done | +512 G arena
constexpr int G_V16 = 0;    // [32] floats (at d_ws+512)
constexpr int G_DD  = 64;   // [238]

// ---------------- LDS arena (floats) ---------------------------------------
constexpr int EEG = 0;      // [16][119]
constexpr int WA  = 1904;   // 140
constexpr int WB  = 2044;   // 140
constexpr int LNT = 2184;   // [119][16]
constexpr int QP4 = 4088;   // [4][119]
constexpr int Z4  = 4564;   // [4][119]
constexpr int UD  = 5040;   // [119]
constexpr int WTT = 5160;   // [119]
constexpr int WVV = 5280;   // [119]
constexpr int VT  = 5400;   // [14]
constexpr int SC4 = 5416;   // [4][14]
constexpr int BKQ = 5472;   // [4]
constexpr int CVB = 5476, CBO = 5477;
constexpr int WQH = 5480;   // [16]
constexpr int WKL = 5496;   // [16]
constexpr int WVL = 5512;   // [16]
constexpr int WQT = 5528;   // [16]
constexpr int CST = 5544;   // [1]
constexpr int AC  = 5548;   // [16]
constexpr int BC  = 5564;   // [16]
constexpr int G1L = 5580;   // [30]
constexpr int MXT = 5612;   // [512] max_fc_w transposed [c][16]
constexpr int MXB = 6124;   // [16]
constexpr int WK2 = 6852;   // [16]  Wk^T weQ
constexpr int C2K = 6868;   // [16]  Wk^T bq
constexpr int CQK = 6884;   // [1]   weQ.bk
constexpr int CBK = 6885;   // [1]   bq.bk
constexpr int VPS = 8756;   // [119][20] (16B-aligned, padded)
constexpr int S1H = 11136;  // [119]
constexpr int S2H = 11255;  // [119]
constexpr int OWS = 11376;  // [256] out_w[mh] transposed [e][c]
constexpr int OBS = 11632;  // [16]
constexpr int O1W = 11648;  // [15][240] my out1_w rows
constexpr int O1B = 15248;  // [15]
constexpr int O2WS= 15264;  // [30]
constexpr int O2B = 15294;  // [2]
constexpr int FCW = 15296;  // [2]
constexpr int FCB = 15298;  // [2]
constexpr int DDL = 15300;  // [238]
constexpr int HHL = 15538;  // [15]
constexpr int VSL = 15554;  // [32]
constexpr int ARENA = 15586; // 62,344 B

struct Args {
  const float *x, *td_in_w, *td_in_b, *td_out_w, *td_out_b;
  const float *cm_in_w, *cm_in_b, *cm_out_w, *cm_out_b;
  const float *mc_w, *mc_b, *max_fc_w, *max_fc_b, *proj_w;
  const float *ln_g, *ln_b, *fc_w, *fc_b;
  const float *out1_w, *out1_b, *out2_w, *out2_b;
  float *out;
  unsigned int *bar;   // d_ws base
  float *G;            // d_ws + 512
};

__device__ __forceinline__ float sigmf(float v) {
  return 1.0f / (1.0f + __expf(-v));
}

__device__ __forceinline__ void gbar(unsigned int* p) {
  __syncthreads();
  if (threadIdx.x == 0) {
    __hip_atomic_fetch_add(p, 1u, __ATOMIC_ACQ_REL, __HIP_MEMORY_SCOPE_AGENT);
    while (__hip_atomic_load(p, __ATOMIC_RELAXED, __HIP_MEMORY_SCOPE_AGENT) < (unsigned)NWG) {
      __builtin_amdgcn_s_sleep(1);
    }
    __builtin_amdgcn_fence(__ATOMIC_ACQUIRE, "agent");
  }
  __syncthreads();
}

__device__ __forceinline__ float dot119(const float* __restrict__ w,
                                        const float* __restrict__ x,
                                        int lane16) {
  float a0 = 0.f, a1 = 0.f;
#pragma unroll
  for (int t = 0; t < 7; ++t) {
    float wv = w[lane16 + 16 * t];
    float xv = x[lane16 + 16 * t];
    if (t & 1) a1 += wv * xv; else a0 += wv * xv;
  }
  if (lane16 < 7) a0 += w[112 + lane16] * x[112 + lane16];
  float acc = a0 + a1;
#pragma unroll
  for (int m = 1; m < 16; m <<= 1) acc += __shfl_xor(acc, m);
  return acc;
}

__device__ __forceinline__ float dot16f4(const float* __restrict__ x,
                                         const float* __restrict__ w) {
  const float4* xa = (const float4*)x; const float4* wa = (const float4*)w;
  float4 x0 = xa[0], x1 = xa[1], x2 = xa[2], x3 = xa[3];
  float4 w0 = wa[0], w1 = wa[1], w2 = wa[2], w3 = wa[3];
  float d0 = x0.x*w0.x + x0.y*w0.y + x0.z*w0.z + x0.w*w0.w;
  float d1 = x1.x*w1.x + x1.y*w1.y + x1.z*w1.z + x1.w*w1.w;
  float d2 = x2.x*w2.x + x2.y*w2.y + x2.z*w2.z + x2.w*w2.w;
  float d3 = x3.x*w3.x + x3.y*w3.y + x3.z*w3.z + x3.w*w3.w;
  return (d0 + d1) + (d2 + d3);
}

__global__ __launch_bounds__(NT) void fused_cnn_kernel(Args a) {
  __shared__ __align__(16) float S[ARENA];
  const int tid = threadIdx.x;
  const int wgid = blockIdx.x;
  const int grp = tid >> 4;
  const int lane16 = tid & 15;
  float* G = a.G;

  const int s  = wgid >> 2;              // 0: A-stream (m0), 1: B-stream (m3)
  const int i0 = (wgid & 3) * 4;         // v16 slots
  const int mh = s ? 3 : 0;              // heavy cm-MHA
  const int lm = s ? 2 : 1;              // folded light cm-MHA
  const int q4 = wgid & 3;
  const int r0 = q4 * 30;
  const int nr = (q4 == 3) ? 29 : 30;
  const int wavX = s ? WB : WA;

  // ---- P0: stage x + static prefetches ---------------------------------
  for (int t = tid; t < 16 * NOFC; t += NT) {
    int c = t / NOFC, tt = t - c * NOFC;
    S[EEG + t] = a.x[(1 + c) * WLEN + (WLEN - NOFC) + tt];
  }
  if (tid < WLEN) {
    S[WA + tid] = a.x[tid];
    S[WB + tid] = a.x[17 * WLEN + tid];
  }
  if (tid < 512) {                       // max_fc_w transposed [c][16]
    int t16 = tid >> 5, c32 = tid & 31;
    S[MXT + c32 * 16 + t16] = a.max_fc_w[tid];
  }
  if (tid < 16)  S[MXB + tid] = a.max_fc_b[tid];
  if (tid < 256) {                       // heavy out_w transposed [e][c]
    int c = tid >> 4, e = tid & 15;
    S[OWS + e * 16 + c] = a.cm_out_w[mh * 256 + tid];
  }
  if (tid < 16)  S[OBS + tid] = a.cm_out_b[mh * 16 + tid];
  for (int idx = tid; idx < 15 * 238; idx += NT) {    // my out1_w rows
    int rl = idx / 238, c = idx - rl * 238;
    int r = wgid * 15 + rl;
    S[O1W + rl * 240 + c] = (r < NOFC) ? a.out1_w[r * 238 + c] : 0.0f;
  }
  if (tid < 15) {
    int r = wgid * 15 + tid;
    S[O1B + tid] = (r < NOFC) ? a.out1_b[r] : 0.0f;
  }
  if (tid < 30) {
    int o = tid / 15, j = tid - o * 15;
    int r = wgid * 15 + j;
    S[O2WS + tid] = (r < NOFC) ? a.out2_w[o * NOFC + r] : 0.0f;
  }
  if (tid < 2) {
    S[O2B + tid] = a.out2_b[tid];
    S[FCW + tid] = a.fc_w[tid];
    S[FCB + tid] = a.fc_b[tid];
  }
  __syncthreads();

  // ---- A: qp (4 rows, weight-row reuse) + u ----------------------------
  for (int e = grp; e < NOFC; e += 64) {
    const float* wrow = a.td_in_w + e * NOFC;
    float w0 = wrow[lane16], w1 = wrow[lane16 + 16], w2 = wrow[lane16 + 32],
          w3 = wrow[lane16 + 48], w4 = wrow[lane16 + 64], w5 = wrow[lane16 + 80],
          w6 = wrow[lane16 + 96];
    float wt7 = (lane16 < 7) ? wrow[112 + lane16] : 0.0f;
    float b = a.td_in_b[e];
#pragma unroll
    for (int kk = 0; kk < 4; ++kk) {
      const float* x = S + EEG + (i0 + kk) * NOFC;
      float acc = w0 * x[lane16] + w1 * x[lane16 + 16] + w2 * x[lane16 + 32]
                + w3 * x[lane16 + 48] + w4 * x[lane16 + 64] + w5 * x[lane16 + 80]
                + w6 * x[lane16 + 96];
      if (lane16 < 7) acc += wt7 * x[112 + lane16];
#pragma unroll
      for (int mm = 1; mm < 16; mm <<= 1) acc += __shfl_xor(acc, mm);
      if (lane16 == 0) S[QP4 + kk * NOFC + e] = acc + b;
    }
  }
  if (grp >= 55) {                        // u[d] = mc_w[s] . eeg[:,d]
    int d = (grp - 55) * 16 + lane16;
    if (d < NOFC) {
      float acc = 0.f;
#pragma unroll
      for (int i = 0; i < 16; ++i) acc += a.mc_w[s * 16 + i] * S[EEG + i * NOFC + d];
      S[UD + d] = acc;
    }
  }
  __syncthreads();

  // ---- B: z (thread/col, 4 acc) | w~ | LNT | bkq | we-vectors ----------
  if (tid < NOFC) {                       // z_k[t], coalesced col reads
    float a0 = 0.f, a1 = 0.f, a2 = 0.f, a3 = 0.f;
    const float* base = a.td_in_w + NOFC * NOFC + tid;
    for (int e = 0; e < NOFC; ++e) {
      float w = base[e * NOFC];
      a0 += S[QP4 + e] * w;
      a1 += S[QP4 + NOFC + e] * w;
      a2 += S[QP4 + 2 * NOFC + e] * w;
      a3 += S[QP4 + 3 * NOFC + e] * w;
    }
    S[Z4 + tid] = a0; S[Z4 + NOFC + tid] = a1;
    S[Z4 + 2 * NOFC + tid] = a2; S[Z4 + 3 * NOFC + tid] = a3;
  } else if (tid >= 128 && tid < 128 + NOFC) {   // w~[t] = u . out_w[:,t]
    int t = tid - 128;
    float acc = 0.f;
    const float* base = a.td_out_w + t;
    for (int d = 0; d < NOFC; ++d) acc += S[UD + d] * base[d * NOFC];
    S[WTT + t] = acc;
  } else if (tid >= 256 && tid < 256 + NOFC) {   // LNT column
    int t = tid - 256;
    float xv[16]; float mu = 0.f;
#pragma unroll
    for (int c = 0; c < 16; ++c) { xv[c] = S[EEG + c * NOFC + t]; mu += xv[c]; }
    mu *= (1.0f / 16.0f);
    float var = 0.f;
#pragma unroll
    for (int c = 0; c < 16; ++c) { float d = xv[c] - mu; var += d * d; }
    var *= (1.0f / 16.0f);
    float inv = 1.0f / sqrtf(var + 1e-5f);
#pragma unroll
    for (int c = 0; c < 16; ++c)
      S[LNT + t * 16 + c] = (xv[c] - mu) * inv * a.ln_g[c] + a.ln_b[c];
  } else if (tid >= 384 && tid < 448) {          // bkq
    int kk = (tid - 384) >> 4;
    float acc = dot119(S + QP4 + kk * NOFC, a.td_in_b + NOFC, lane16);
    if (lane16 == 0) S[BKQ + kk] = acc;
  } else if (tid >= 448 && tid < 464) {          // weQ heavy
    int e = tid - 448;
    float acc = 0.f;
#pragma unroll
    for (int c = 0; c < 16; ++c) acc += a.proj_w[s * 16 + c] * a.cm_in_w[(mh * 48 + e) * 16 + c];
    S[WQH + e] = acc;
  } else if (tid >= 464 && tid < 480) {          // weK light
    int e = tid - 464;
    float acc = 0.f;
#pragma unroll
    for (int c = 0; c < 16; ++c) acc += a.proj_w[s * 16 + c] * a.cm_in_w[(lm * 48 + 16 + e) * 16 + c];
    S[WKL + e] = acc;
  } else if (tid >= 480 && tid < 496) {          // weV light
    int e = tid - 480;
    float acc = 0.f;
#pragma unroll
    for (int c = 0; c < 16; ++c) acc += a.proj_w[s * 16 + c] * a.cm_in_w[(lm * 48 + 32 + e) * 16 + c];
    S[WVL + e] = acc;
  }
  __syncthreads();

  // ---- C: wv | wk2/c2k/cqk/cbk | vp staging | td scores ----------------
  if (tid < NOFC) {                       // wv[t] = w~ . Wv[:,t]
    float acc = 0.f;
    const float* base = a.td_in_w + 2 * NOFC * NOFC + tid;
    for (int e = 0; e < NOFC; ++e) acc += S[WTT + e] * base[e * NOFC];
    S[WVV + tid] = acc;
  } else if (tid == 124) {                // cqk = weQ . bk
    float acc = 0.f;
#pragma unroll
    for (int e = 0; e < 16; ++e) acc += S[WQH + e] * a.cm_in_b[mh * 48 + 16 + e];
    S[CQK] = acc;
  } else if (tid == 125) {                // cbk = bq . bk
    float acc = 0.f;
#pragma unroll
    for (int e = 0; e < 16; ++e) acc += a.cm_in_b[mh * 48 + e] * a.cm_in_b[mh * 48 + 16 + e];
    S[CBK] = acc;
  } else if (tid >= 128 && tid < 144) {   // wk2[c] = sum_e weQ[e]*Wk[e][c]
    int c = tid - 128;
    float acc = 0.f;
#pragma unroll
    for (int e = 0; e < 16; ++e) acc += S[WQH + e] * a.cm_in_w[(mh * 48 + 16 + e) * 16 + c];
    S[WK2 + c] = acc;
  } else if (tid >= 144 && tid < 160) {   // c2k[c] = sum_e bq[e]*Wk[e][c]
    int c = tid - 144;
    float acc = 0.f;
#pragma unroll
    for (int e = 0; e < 16; ++e) acc += a.cm_in_b[mh * 48 + e] * a.cm_in_w[(mh * 48 + 16 + e) * 16 + c];
    S[C2K + c] = acc;
  } else if (tid >= 160 && tid < 592) {   // vp staging (1904 outs, 5 rounds)
    for (int o = tid - 160; o < 1904; o += 432) {
      int u = o >> 4, e = o & 15;
      S[VPS + u * 20 + e] = dot16f4(S + LNT + u * 16, a.cm_in_w + (mh * 48 + 32 + e) * 16)
                            + a.cm_in_b[mh * 48 + 32 + e];
    }
  }
  if (grp >= 37) {                        // scores, 3 rounds (z done in B)
#pragma unroll
    for (int rnd = 0; rnd < 3; ++rnd) {
      int idx = (grp - 37) + rnd * 27;
      if (idx < 56) {
        int kk = idx / TDN, j = idx - kk * TDN;
        float acc = dot119(S + wavX + j, S + Z4 + kk * NOFC, lane16);
        if (lane16 == 0)
          S[SC4 + kk * TDN + j] = 0.09166984970282113f * (acc + S[BKQ + kk]);
      }
    }
  }
  __syncthreads();

  // ---- D: vtil | softmax | cvb/cbo | wq~/cst/A1/B1 | s1/s2 -------------
  if (grp < TDN) {                        // vtil
    float acc = dot119(S + wavX + grp, S + WVV, lane16);
    if (lane16 == 0) S[VT + grp] = acc;
  } else if (tid >= 224 && tid < 228) {   // softmax
    int k = tid - 224;
    float* r = S + SC4 + k * TDN;
    float mx = r[0];
#pragma unroll
    for (int j = 1; j < TDN; ++j) mx = fmaxf(mx, r[j]);
    float sum = 0.f;
#pragma unroll
    for (int j = 0; j < TDN; ++j) { float p = __expf(r[j] - mx); r[j] = p; sum += p; }
    float inv = 1.0f / sum;
#pragma unroll
    for (int j = 0; j < TDN; ++j) r[j] *= inv;
  } else if (grp == 15) {                 // cvb = bv . w~
    float acc = dot119(a.td_in_b + 2 * NOFC, S + WTT, lane16);
    if (lane16 == 0) S[CVB] = acc;
  } else if (grp == 16) {                 // cbo = u . out_b
    float acc = dot119(S + UD, a.td_out_b, lane16);
    if (lane16 == 0) S[CBO] = acc;
  } else if (tid >= 288 && tid < 304) {   // wq~[c]
    int c = tid - 288;
    float acc = 0.f;
#pragma unroll
    for (int e = 0; e < 16; ++e) acc += a.cm_in_w[(lm * 48 + e) * 16 + c] * S[WKL + e];
    S[WQT + c] = acc;
  } else if (tid == 304) {                // cst
    float acc = 0.f;
#pragma unroll
    for (int e = 0; e < 16; ++e) acc += a.cm_in_b[lm * 48 + e] * S[WKL + e];
    S[CST] = acc;
  } else if (tid >= 320 && tid < 336) {   // A1[c]
    int c = tid - 320;
    float acc = 0.f;
#pragma unroll
    for (int e = 0; e < 16; ++e) acc += a.cm_out_w[lm * 256 + c * 16 + e] * S[WVL + e];
    S[AC + c] = acc;
  } else if (tid >= 336 && tid < 352) {   // B1[c]
    int c = tid - 336;
    float acc = 0.f;
#pragma unroll
    for (int e = 0; e < 16; ++e) acc += a.cm_out_w[lm * 256 + c * 16 + e] * a.cm_in_b[lm * 48 + 32 + e];
    S[BC + c] = acc + a.cm_out_b[lm * 16 + c];
  }
  if (tid >= 512 && tid < 750) {          // s1/s2 via wk2/c2k over LNT
    int idx = tid - 512;
    int u = (idx < NOFC) ? idx : idx - NOFC;
    const float* lr = S + LNT + u * 16;
    float acc = 0.f;
    if (idx < NOFC) {
#pragma unroll
      for (int c = 0; c < 16; ++c) acc += S[WK2 + c] * lr[c];
      S[S1H + u] = acc + S[CQK];
    } else {
#pragma unroll
      for (int c = 0; c < 16; ++c) acc += S[C2K + c] * lr[c];
      S[S2H + u] = acc + S[CBK];
    }
  }
  __syncthreads();

  // ---- E: v16 -> G | g1 -------------------------------------------------
  if (tid < 4) {
    float acc = 0.f;
#pragma unroll
    for (int j = 0; j < TDN; ++j) acc += S[SC4 + tid * TDN + j] * S[VT + j];
    float v = acc + S[CVB] + S[CBO] + a.mc_b[s];
    G[G_V16 + s * 16 + i0 + tid] = fmaxf(v, 0.f);
  } else if (tid >= 32 && tid < 62) {
    int rl = tid - 32;
    if (rl < nr) {
      int t = r0 + rl;
      float acc = S[CST];
#pragma unroll
      for (int c = 0; c < 16; ++c) acc += S[LNT + t * 16 + c] * S[WQT + c];
      S[G1L + rl] = acc;
    }
  }
  gbar(a.bar + 0);

  // ---- argmax (register, replicated) ------------------------------------
  if (tid < 32) S[VSL + tid] = G[G_V16 + tid];
  __syncthreads();
  int mi;
  {
    float wl = S[MXB + lane16];
#pragma unroll
    for (int c = 0; c < 32; ++c) wl += S[MXT + c * 16 + lane16] * S[VSL + c];
    wl = fmaxf(wl, 0.f);
    float mx = wl;
#pragma unroll
    for (int d = 1; d < 16; d <<= 1) mx = fmaxf(mx, __shfl_xor(mx, d));
    int cand = (wl == mx) ? lane16 : 99;
#pragma unroll
    for (int d = 1; d < 16; d <<= 1) cand = min(cand, __shfl_xor(cand, d));
    mi = min(cand, TDN - 1);
  }

  // ---- attention rows -> G_DD -------------------------------------------
  if (grp < nr) {
    const int t = r0 + grp;
    const float wselq = S[wavX + t + mi];
    float p[8];
    float sum = 0.f;
#pragma unroll
    for (int cc = 0; cc < 8; ++cc) {
      int u = lane16 + cc * 16;
      float e1 = 0.f;
      if (u < NOFC)
        e1 = __expf(0.25f * (wselq * S[S1H + u] + S[S2H + u]));
      p[cc] = e1;
      sum += e1;
    }
#pragma unroll
    for (int d = 1; d < 16; d <<= 1) sum += __shfl_xor(sum, d);
    float inv = 1.0f / sum;

    float oa[16];
#pragma unroll
    for (int e = 0; e < 16; ++e) oa[e] = 0.f;
#pragma unroll
    for (int cc = 0; cc < 8; ++cc) {
      int u = lane16 + cc * 16;
      if (u < NOFC) {
        const float4* v4 = (const float4*)(S + VPS + u * 20);
        float4 v0 = v4[0], v1 = v4[1], v2 = v4[2], v3 = v4[3];
        float pv = p[cc];
        oa[0] += pv*v0.x; oa[1] += pv*v0.y; oa[2] += pv*v0.z; oa[3] += pv*v0.w;
        oa[4] += pv*v1.x; oa[5] += pv*v1.y; oa[6] += pv*v1.z; oa[7] += pv*v1.w;
        oa[8] += pv*v2.x; oa[9] += pv*v2.y; oa[10] += pv*v2.z; oa[11] += pv*v2.w;
        oa[12] += pv*v3.x; oa[13] += pv*v3.y; oa[14] += pv*v3.z; oa[15] += pv*v3.w;
      }
    }
#pragma unroll
    for (int e = 0; e < 16; ++e) {
#pragma unroll
      for (int d = 1; d < 16; d <<= 1) oa[e] += __shfl_xor(oa[e], d);
    }
    float oc = S[OBS + lane16];
#pragma unroll
    for (int e = 0; e < 16; ++e) oc += oa[e] * inv * S[OWS + e * 16 + lane16];
    float dA = oc * S[AC + lane16];
    float dB = oc * S[BC + lane16];
#pragma unroll
    for (int d = 1; d < 16; d <<= 1) {
      dA += __shfl_xor(dA, d);
      dB += __shfl_xor(dB, d);
    }
    const float g = S[G1L + grp];
    float s0 = 0.f, s1a = 0.f;
#pragma unroll
    for (int cc = 0; cc < 8; ++cc) {
      int u = lane16 + cc * 16;
      if (u < NOFC) {
        float w = S[wavX + u + mi];
        float e1 = __expf(0.25f * g * w);
        s0 += e1; s1a += e1 * w;
      }
    }
#pragma unroll
    for (int d = 1; d < 16; d <<= 1) {
      s0 += __shfl_xor(s0, d);
      s1a += __shfl_xor(s1a, d);
    }
    float h = s1a / s0;
    float dval = h * dA + dB;
    if (lane16 == 0)
      G[G_DD + s * NOFC + t] = sigmf(S[FCW + s] * dval + S[FCB + s]);
  }
  gbar(a.bar + 16);

  // ---- head: dd -> LDS, 15 out1 rows, out2 via 2 atomics ----------------
  if (tid < 238) S[DDL + tid] = G[G_DD + tid];
  __syncthreads();
  if (grp < 15) {
    int r = wgid * 15 + grp;
    float acc = 0.f;
#pragma unroll
    for (int k = 0; k < 15; ++k) {
      int c = lane16 + 16 * k;
      if (c < 238) acc += S[O1W + grp * 240 + c] * S[DDL + c];
    }
#pragma unroll
    for (int d = 1; d < 16; d <<= 1) acc += __shfl_xor(acc, d);
    if (lane16 == 0)
      S[HHL + grp] = (r < NOFC) ? sigmf(acc + S[O1B + grp]) : 0.0f;
  }
  __syncthreads();
  if (tid == 0) {
    float p0 = 0.f, p1 = 0.f;
#pragma unroll
    for (int j = 0; j < 15; ++j) {
      p0 += S[O2WS + j] * S[HHL + j];
      p1 += S[O2WS + 15 + j] * S[HHL + j];
    }
    float* acc = (float*)((char*)a.bar + 128);
    unsigned int* done = (unsigned int*)((char*)a.bar + 192);
    __hip_atomic_fetch_add(acc + 0, p0, __ATOMIC_RELAXED, __HIP_MEMORY_SCOPE_AGENT);
    __hip_atomic_fetch_add(acc + 1, p1, __ATOMIC_RELAXED, __HIP_MEMORY_SCOPE_AGENT);
    unsigned old = __hip_atomic_fetch_add(done, 1u, __ATOMIC_ACQ_REL, __HIP_MEMORY_SCOPE_AGENT);
    if (old == NWG - 1) {
      __builtin_amdgcn_fence(__ATOMIC_ACQUIRE, "agent");
      float a0 = __hip_atomic_load(acc + 0, __ATOMIC_RELAXED, __HIP_MEMORY_SCOPE_AGENT);
      float a1 = __hip_atomic_load(acc + 1, __ATOMIC_RELAXED, __HIP_MEMORY_SCOPE_AGENT);
      a.out[0] = sigmf(a0 + S[O2B + 0]);
      a.out[1] = sigmf(a1 + S[O2B + 1]);
    }
  }
}

extern "C" void kernel_launch(void* const* d_in, const int* in_sizes, int n_in,
                              void* d_out, int out_size, void* d_ws, size_t ws_size,
                              hipStream_t stream) {
  Args a;
  a.x        = (const float*)d_in[0];
  a.td_in_w  = (const float*)d_in[1];
  a.td_in_b  = (const float*)d_in[2];
  a.td_out_w = (const float*)d_in[3];
  a.td_out_b = (const float*)d_in[4];
  a.cm_in_w  = (const float*)d_in[5];
  a.cm_in_b  = (const float*)d_in[6];
  a.cm_out_w = (const float*)d_in[7];
  a.cm_out_b = (const float*)d_in[8];
  a.mc_w     = (const float*)d_in[9];
  a.mc_b     = (const float*)d_in[10];
  a.max_fc_w = (const float*)d_in[11];
  a.max_fc_b = (const float*)d_in[12];
  a.proj_w   = (const float*)d_in[13];
  a.ln_g     = (const float*)d_in[14];
  a.ln_b     = (const float*)d_in[15];
  a.fc_w     = (const float*)d_in[16];
  a.fc_b     = (const float*)d_in[17];
  a.out1_w   = (const float*)d_in[18];
  a.out1_b   = (const float*)d_in[19];
  a.out2_w   = (const float*)d_in[20];
  a.out2_b   = (const float*)d_in[21];
  a.out      = (float*)d_out;
  a.bar      = (unsigned int*)d_ws;
  a.G        = (float*)((char*)d_ws + 512);

  // zero barriers + out2 accumulators + done counter each call.
  hipMemsetAsync(d_ws, 0, 512, stream);
  fused_cnn_kernel<<<dim3(NWG), dim3(NT), 0, stream>>>(a);
}

// Round 12
// 31.561 us; speedup vs baseline: 1.7129x; 1.0623x over previous
//
#include <hip/hip_runtime.h>
#include <math.h>

// ---------------------------------------------------------------------------
// CNN_88098369175791 — R12: R11 minus one barrier interval and two syncs.
//  * u -> P0 (reads global x directly), w~ -> A, wv -> B, vtil -> C,
//    softmax+v16 fused per-k thread in D  => phase E eliminated.
//  * argmax reads G_V16 directly (no LDS staging sync).
//  * head out1 reads G_DD directly (no DDL staging sync).
// ---------------------------------------------------------------------------

#define NWG 8
#define NT  1024

constexpr int WLEN = 140;
constexpr int TDN  = 14;
constexpr int NOFC = 119;

// d_ws: [0,64) bar0 | [64,128) bar1 | +128 acc[2] | +192 done | +512 G arena
constexpr int G_V16 = 0;    // [32] floats (at d_ws+512)
constexpr int G_DD  = 64;   // [238]

// ---------------- LDS arena (floats) ---------------------------------------
constexpr int EEG = 0;      // [16][119]
constexpr int WA  = 1904;   // 140
constexpr int WB  = 2044;   // 140
constexpr int LNT = 2184;   // [119][16]
constexpr int QP4 = 4088;   // [4][119]
constexpr int Z4  = 4564;   // [4][119]
constexpr int UD  = 5040;   // [119]
constexpr int WTT = 5160;   // [119]
constexpr int WVV = 5280;   // [119]
constexpr int VT  = 5400;   // [14]
constexpr int SC4 = 5416;   // [4][14]
constexpr int BKQ = 5472;   // [4]
constexpr int CVB = 5476, CBO = 5477;
constexpr int WQH = 5480;   // [16]
constexpr int WKL = 5496;   // [16]
constexpr int WVL = 5512;   // [16]
constexpr int WQT = 5528;   // [16]
constexpr int CST = 5544;   // [1]
constexpr int AC  = 5548;   // [16]
constexpr int BC  = 5564;   // [16]
constexpr int G1L = 5580;   // [30]
constexpr int MXT = 5612;   // [512] max_fc_w transposed [c][16]
constexpr int MXB = 6124;   // [16]
constexpr int WK2 = 6852;   // [16]  Wk^T weQ
constexpr int C2K = 6868;   // [16]  Wk^T bq
constexpr int CQK = 6884;   // [1]   weQ.bk
constexpr int CBK = 6885;   // [1]   bq.bk
constexpr int VPS = 8756;   // [119][20] (16B-aligned, padded)
constexpr int S1H = 11136;  // [119]
constexpr int S2H = 11255;  // [119]
constexpr int OWS = 11376;  // [256] out_w[mh] transposed [e][c]
constexpr int OBS = 11632;  // [16]
constexpr int O1W = 11648;  // [15][240] my out1_w rows
constexpr int O1B = 15248;  // [15]
constexpr int O2WS= 15264;  // [30]
constexpr int O2B = 15294;  // [2]
constexpr int FCW = 15296;  // [2]
constexpr int FCB = 15298;  // [2]
constexpr int HHL = 15300;  // [15]
constexpr int ARENA = 15316; // 61,264 B

struct Args {
  const float *x, *td_in_w, *td_in_b, *td_out_w, *td_out_b;
  const float *cm_in_w, *cm_in_b, *cm_out_w, *cm_out_b;
  const float *mc_w, *mc_b, *max_fc_w, *max_fc_b, *proj_w;
  const float *ln_g, *ln_b, *fc_w, *fc_b;
  const float *out1_w, *out1_b, *out2_w, *out2_b;
  float *out;
  unsigned int *bar;   // d_ws base
  float *G;            // d_ws + 512
};

__device__ __forceinline__ float sigmf(float v) {
  return 1.0f / (1.0f + __expf(-v));
}

__device__ __forceinline__ void gbar(unsigned int* p) {
  __syncthreads();
  if (threadIdx.x == 0) {
    __hip_atomic_fetch_add(p, 1u, __ATOMIC_ACQ_REL, __HIP_MEMORY_SCOPE_AGENT);
    while (__hip_atomic_load(p, __ATOMIC_RELAXED, __HIP_MEMORY_SCOPE_AGENT) < (unsigned)NWG) {
      __builtin_amdgcn_s_sleep(1);
    }
    __builtin_amdgcn_fence(__ATOMIC_ACQUIRE, "agent");
  }
  __syncthreads();
}

__device__ __forceinline__ float dot119(const float* __restrict__ w,
                                        const float* __restrict__ x,
                                        int lane16) {
  float a0 = 0.f, a1 = 0.f;
#pragma unroll
  for (int t = 0; t < 7; ++t) {
    float wv = w[lane16 + 16 * t];
    float xv = x[lane16 + 16 * t];
    if (t & 1) a1 += wv * xv; else a0 += wv * xv;
  }
  if (lane16 < 7) a0 += w[112 + lane16] * x[112 + lane16];
  float acc = a0 + a1;
#pragma unroll
  for (int m = 1; m < 16; m <<= 1) acc += __shfl_xor(acc, m);
  return acc;
}

__device__ __forceinline__ float dot16f4(const float* __restrict__ x,
                                         const float* __restrict__ w) {
  const float4* xa = (const float4*)x; const float4* wa = (const float4*)w;
  float4 x0 = xa[0], x1 = xa[1], x2 = xa[2], x3 = xa[3];
  float4 w0 = wa[0], w1 = wa[1], w2 = wa[2], w3 = wa[3];
  float d0 = x0.x*w0.x + x0.y*w0.y + x0.z*w0.z + x0.w*w0.w;
  float d1 = x1.x*w1.x + x1.y*w1.y + x1.z*w1.z + x1.w*w1.w;
  float d2 = x2.x*w2.x + x2.y*w2.y + x2.z*w2.z + x2.w*w2.w;
  float d3 = x3.x*w3.x + x3.y*w3.y + x3.z*w3.z + x3.w*w3.w;
  return (d0 + d1) + (d2 + d3);
}

__global__ __launch_bounds__(NT) void fused_cnn_kernel(Args a) {
  __shared__ __align__(16) float S[ARENA];
  const int tid = threadIdx.x;
  const int wgid = blockIdx.x;
  const int grp = tid >> 4;
  const int lane16 = tid & 15;
  float* G = a.G;

  const int s  = wgid >> 2;              // 0: A-stream (m0), 1: B-stream (m3)
  const int i0 = (wgid & 3) * 4;         // v16 slots
  const int mh = s ? 3 : 0;              // heavy cm-MHA
  const int lm = s ? 2 : 1;              // folded light cm-MHA
  const int q4 = wgid & 3;
  const int r0 = q4 * 30;
  const int nr = (q4 == 3) ? 29 : 30;
  const int wavX = s ? WB : WA;

  // ---- P0: stage x + static prefetches + u (direct from global x) ------
  for (int t = tid; t < 16 * NOFC; t += NT) {
    int c = t / NOFC, tt = t - c * NOFC;
    S[EEG + t] = a.x[(1 + c) * WLEN + (WLEN - NOFC) + tt];
  }
  if (tid < WLEN) {
    S[WA + tid] = a.x[tid];
    S[WB + tid] = a.x[17 * WLEN + tid];
  }
  if (tid < 512) {                       // max_fc_w transposed [c][16]
    int t16 = tid >> 5, c32 = tid & 31;
    S[MXT + c32 * 16 + t16] = a.max_fc_w[tid];
  }
  if (tid < 16)  S[MXB + tid] = a.max_fc_b[tid];
  if (tid < 256) {                       // heavy out_w transposed [e][c]
    int c = tid >> 4, e = tid & 15;
    S[OWS + e * 16 + c] = a.cm_out_w[mh * 256 + tid];
  }
  if (tid < 16)  S[OBS + tid] = a.cm_out_b[mh * 16 + tid];
  for (int idx = tid; idx < 15 * 238; idx += NT) {    // my out1_w rows
    int rl = idx / 238, c = idx - rl * 238;
    int r = wgid * 15 + rl;
    S[O1W + rl * 240 + c] = (r < NOFC) ? a.out1_w[r * 238 + c] : 0.0f;
  }
  if (tid < 15) {
    int r = wgid * 15 + tid;
    S[O1B + tid] = (r < NOFC) ? a.out1_b[r] : 0.0f;
  }
  if (tid < 30) {
    int o = tid / 15, j = tid - o * 15;
    int r = wgid * 15 + j;
    S[O2WS + tid] = (r < NOFC) ? a.out2_w[o * NOFC + r] : 0.0f;
  }
  if (tid < 2) {
    S[O2B + tid] = a.out2_b[tid];
    S[FCW + tid] = a.fc_w[tid];
    S[FCB + tid] = a.fc_b[tid];
  }
  if (tid >= 896 && tid < 896 + NOFC) {  // u[d] = mc_w[s] . x rows (global)
    int d = tid - 896;
    float acc = 0.f;
#pragma unroll
    for (int i = 0; i < 16; ++i)
      acc += a.mc_w[s * 16 + i] * a.x[(1 + i) * WLEN + (WLEN - NOFC) + d];
    S[UD + d] = acc;
  }
  __syncthreads();

  // ---- A: qp (4 rows, 48 groups) | w~ (thread/col) ---------------------
  if (grp < 48) {
    for (int e = grp; e < NOFC; e += 48) {
      const float* wrow = a.td_in_w + e * NOFC;
      float w0 = wrow[lane16], w1 = wrow[lane16 + 16], w2 = wrow[lane16 + 32],
            w3 = wrow[lane16 + 48], w4 = wrow[lane16 + 64], w5 = wrow[lane16 + 80],
            w6 = wrow[lane16 + 96];
      float wt7 = (lane16 < 7) ? wrow[112 + lane16] : 0.0f;
      float b = a.td_in_b[e];
#pragma unroll
      for (int kk = 0; kk < 4; ++kk) {
        const float* x = S + EEG + (i0 + kk) * NOFC;
        float acc = w0 * x[lane16] + w1 * x[lane16 + 16] + w2 * x[lane16 + 32]
                  + w3 * x[lane16 + 48] + w4 * x[lane16 + 64] + w5 * x[lane16 + 80]
                  + w6 * x[lane16 + 96];
        if (lane16 < 7) acc += wt7 * x[112 + lane16];
#pragma unroll
        for (int mm = 1; mm < 16; mm <<= 1) acc += __shfl_xor(acc, mm);
        if (lane16 == 0) S[QP4 + kk * NOFC + e] = acc + b;
      }
    }
  } else if (tid >= 768 && tid < 768 + NOFC) {   // w~[t] = u . out_w[:,t]
    int t = tid - 768;
    float acc = 0.f;
    const float* base = a.td_out_w + t;
    for (int d = 0; d < NOFC; ++d) acc += S[UD + d] * base[d * NOFC];
    S[WTT + t] = acc;
  }
  __syncthreads();

  // ---- B: z | LNT | wv | bkq | we-vectors ------------------------------
  if (tid < NOFC) {                       // z_k[t], coalesced col reads
    float a0 = 0.f, a1 = 0.f, a2 = 0.f, a3 = 0.f;
    const float* base = a.td_in_w + NOFC * NOFC + tid;
    for (int e = 0; e < NOFC; ++e) {
      float w = base[e * NOFC];
      a0 += S[QP4 + e] * w;
      a1 += S[QP4 + NOFC + e] * w;
      a2 += S[QP4 + 2 * NOFC + e] * w;
      a3 += S[QP4 + 3 * NOFC + e] * w;
    }
    S[Z4 + tid] = a0; S[Z4 + NOFC + tid] = a1;
    S[Z4 + 2 * NOFC + tid] = a2; S[Z4 + 3 * NOFC + tid] = a3;
  } else if (tid >= 128 && tid < 128 + NOFC) {   // LNT column
    int t = tid - 128;
    float xv[16]; float mu = 0.f;
#pragma unroll
    for (int c = 0; c < 16; ++c) { xv[c] = S[EEG + c * NOFC + t]; mu += xv[c]; }
    mu *= (1.0f / 16.0f);
    float var = 0.f;
#pragma unroll
    for (int c = 0; c < 16; ++c) { float d = xv[c] - mu; var += d * d; }
    var *= (1.0f / 16.0f);
    float inv = 1.0f / sqrtf(var + 1e-5f);
#pragma unroll
    for (int c = 0; c < 16; ++c)
      S[LNT + t * 16 + c] = (xv[c] - mu) * inv * a.ln_g[c] + a.ln_b[c];
  } else if (tid >= 256 && tid < 256 + NOFC) {   // wv[t] = w~ . Wv[:,t]
    int t = tid - 256;
    float acc = 0.f;
    const float* base = a.td_in_w + 2 * NOFC * NOFC + t;
    for (int e = 0; e < NOFC; ++e) acc += S[WTT + e] * base[e * NOFC];
    S[WVV + t] = acc;
  } else if (tid >= 384 && tid < 448) {          // bkq
    int kk = (tid - 384) >> 4;
    float acc = dot119(S + QP4 + kk * NOFC, a.td_in_b + NOFC, lane16);
    if (lane16 == 0) S[BKQ + kk] = acc;
  } else if (tid >= 448 && tid < 464) {          // weQ heavy
    int e = tid - 448;
    float acc = 0.f;
#pragma unroll
    for (int c = 0; c < 16; ++c) acc += a.proj_w[s * 16 + c] * a.cm_in_w[(mh * 48 + e) * 16 + c];
    S[WQH + e] = acc;
  } else if (tid >= 464 && tid < 480) {          // weK light
    int e = tid - 464;
    float acc = 0.f;
#pragma unroll
    for (int c = 0; c < 16; ++c) acc += a.proj_w[s * 16 + c] * a.cm_in_w[(lm * 48 + 16 + e) * 16 + c];
    S[WKL + e] = acc;
  } else if (tid >= 480 && tid < 496) {          // weV light
    int e = tid - 480;
    float acc = 0.f;
#pragma unroll
    for (int c = 0; c < 16; ++c) acc += a.proj_w[s * 16 + c] * a.cm_in_w[(lm * 48 + 32 + e) * 16 + c];
    S[WVL + e] = acc;
  }
  __syncthreads();

  // ---- C: vtil | cvb/cbo | wk2/c2k/cqk/cbk | wq~/cst/A1/B1 | vp | scores
  if (grp < TDN) {                        // vtil[j] = win_j . wv
    float acc = dot119(S + wavX + grp, S + WVV, lane16);
    if (lane16 == 0) S[VT + grp] = acc;
  } else if (grp == 14) {                 // cvb = bv . w~
    float acc = dot119(a.td_in_b + 2 * NOFC, S + WTT, lane16);
    if (lane16 == 0) S[CVB] = acc;
  } else if (grp == 15) {                 // cbo = u . out_b
    float acc = dot119(S + UD, a.td_out_b, lane16);
    if (lane16 == 0) S[CBO] = acc;
  } else if (tid >= 256 && tid < 272) {   // wk2[c] = sum_e weQ[e]*Wk[e][c]
    int c = tid - 256;
    float acc = 0.f;
#pragma unroll
    for (int e = 0; e < 16; ++e) acc += S[WQH + e] * a.cm_in_w[(mh * 48 + 16 + e) * 16 + c];
    S[WK2 + c] = acc;
  } else if (tid >= 272 && tid < 288) {   // c2k[c] = sum_e bq[e]*Wk[e][c]
    int c = tid - 272;
    float acc = 0.f;
#pragma unroll
    for (int e = 0; e < 16; ++e) acc += a.cm_in_b[mh * 48 + e] * a.cm_in_w[(mh * 48 + 16 + e) * 16 + c];
    S[C2K + c] = acc;
  } else if (tid == 288) {                // cqk = weQ . bk
    float acc = 0.f;
#pragma unroll
    for (int e = 0; e < 16; ++e) acc += S[WQH + e] * a.cm_in_b[mh * 48 + 16 + e];
    S[CQK] = acc;
  } else if (tid == 289) {                // cbk = bq . bk
    float acc = 0.f;
#pragma unroll
    for (int e = 0; e < 16; ++e) acc += a.cm_in_b[mh * 48 + e] * a.cm_in_b[mh * 48 + 16 + e];
    S[CBK] = acc;
  } else if (tid >= 304 && tid < 320) {   // wq~[c]
    int c = tid - 304;
    float acc = 0.f;
#pragma unroll
    for (int e = 0; e < 16; ++e) acc += a.cm_in_w[(lm * 48 + e) * 16 + c] * S[WKL + e];
    S[WQT + c] = acc;
  } else if (tid == 320) {                // cst
    float acc = 0.f;
#pragma unroll
    for (int e = 0; e < 16; ++e) acc += a.cm_in_b[lm * 48 + e] * S[WKL + e];
    S[CST] = acc;
  } else if (tid >= 336 && tid < 352) {   // A1[c]
    int c = tid - 336;
    float acc = 0.f;
#pragma unroll
    for (int e = 0; e < 16; ++e) acc += a.cm_out_w[lm * 256 + c * 16 + e] * S[WVL + e];
    S[AC + c] = acc;
  } else if (tid >= 352 && tid < 368) {   // B1[c]
    int c = tid - 352;
    float acc = 0.f;
#pragma unroll
    for (int e = 0; e < 16; ++e) acc += a.cm_out_w[lm * 256 + c * 16 + e] * a.cm_in_b[lm * 48 + 32 + e];
    S[BC + c] = acc + a.cm_out_b[lm * 16 + c];
  } else if (tid >= 368 && tid < 640) {   // vp staging (1904 outs, 7 rounds)
    for (int o = tid - 368; o < 1904; o += 272) {
      int u = o >> 4, e = o & 15;
      S[VPS + u * 20 + e] = dot16f4(S + LNT + u * 16, a.cm_in_w + (mh * 48 + 32 + e) * 16)
                            + a.cm_in_b[mh * 48 + 32 + e];
    }
  }
  if (grp >= 40) {                        // scores, 3 rounds (z from B)
#pragma unroll
    for (int rnd = 0; rnd < 3; ++rnd) {
      int idx = (grp - 40) + rnd * 24;
      if (idx < 56) {
        int kk = idx / TDN, j = idx - kk * TDN;
        float acc = dot119(S + wavX + j, S + Z4 + kk * NOFC, lane16);
        if (lane16 == 0)
          S[SC4 + kk * TDN + j] = 0.09166984970282113f * (acc + S[BKQ + kk]);
      }
    }
  }
  __syncthreads();

  // ---- D: fused softmax+v16 | g1 | s1/s2 -------------------------------
  if (tid < 4) {                          // softmax . vtil, inline, -> G
    const float* r = S + SC4 + tid * TDN;
    float mx = r[0];
#pragma unroll
    for (int j = 1; j < TDN; ++j) mx = fmaxf(mx, r[j]);
    float sum = 0.f, acc = 0.f;
#pragma unroll
    for (int j = 0; j < TDN; ++j) {
      float p = __expf(r[j] - mx);
      sum += p;
      acc += p * S[VT + j];
    }
    float v = acc / sum + S[CVB] + S[CBO] + a.mc_b[s];
    G[G_V16 + s * 16 + i0 + tid] = fmaxf(v, 0.f);
  } else if (tid >= 32 && tid < 62) {     // g1
    int rl = tid - 32;
    if (rl < nr) {
      int t = r0 + rl;
      float acc = S[CST];
#pragma unroll
      for (int c = 0; c < 16; ++c) acc += S[LNT + t * 16 + c] * S[WQT + c];
      S[G1L + rl] = acc;
    }
  }
  if (tid >= 512 && tid < 750) {          // s1/s2 via wk2/c2k over LNT
    int idx = tid - 512;
    int u = (idx < NOFC) ? idx : idx - NOFC;
    const float* lr = S + LNT + u * 16;
    float acc = 0.f;
    if (idx < NOFC) {
#pragma unroll
      for (int c = 0; c < 16; ++c) acc += S[WK2 + c] * lr[c];
      S[S1H + u] = acc + S[CQK];
    } else {
#pragma unroll
      for (int c = 0; c < 16; ++c) acc += S[C2K + c] * lr[c];
      S[S2H + u] = acc + S[CBK];
    }
  }
  gbar(a.bar + 0);

  // ---- argmax (register, direct G reads — no staging sync) --------------
  int mi;
  {
    float wl = S[MXB + lane16];
#pragma unroll
    for (int c = 0; c < 32; ++c) wl += S[MXT + c * 16 + lane16] * G[G_V16 + c];
    wl = fmaxf(wl, 0.f);
    float mx = wl;
#pragma unroll
    for (int d = 1; d < 16; d <<= 1) mx = fmaxf(mx, __shfl_xor(mx, d));
    int cand = (wl == mx) ? lane16 : 99;
#pragma unroll
    for (int d = 1; d < 16; d <<= 1) cand = min(cand, __shfl_xor(cand, d));
    mi = min(cand, TDN - 1);
  }

  // ---- attention rows -> G_DD -------------------------------------------
  if (grp < nr) {
    const int t = r0 + grp;
    const float wselq = S[wavX + t + mi];
    float p[8];
    float sum = 0.f;
#pragma unroll
    for (int cc = 0; cc < 8; ++cc) {
      int u = lane16 + cc * 16;
      float e1 = 0.f;
      if (u < NOFC)
        e1 = __expf(0.25f * (wselq * S[S1H + u] + S[S2H + u]));
      p[cc] = e1;
      sum += e1;
    }
#pragma unroll
    for (int d = 1; d < 16; d <<= 1) sum += __shfl_xor(sum, d);
    float inv = 1.0f / sum;

    float oa[16];
#pragma unroll
    for (int e = 0; e < 16; ++e) oa[e] = 0.f;
#pragma unroll
    for (int cc = 0; cc < 8; ++cc) {
      int u = lane16 + cc * 16;
      if (u < NOFC) {
        const float4* v4 = (const float4*)(S + VPS + u * 20);
        float4 v0 = v4[0], v1 = v4[1], v2 = v4[2], v3 = v4[3];
        float pv = p[cc];
        oa[0] += pv*v0.x; oa[1] += pv*v0.y; oa[2] += pv*v0.z; oa[3] += pv*v0.w;
        oa[4] += pv*v1.x; oa[5] += pv*v1.y; oa[6] += pv*v1.z; oa[7] += pv*v1.w;
        oa[8] += pv*v2.x; oa[9] += pv*v2.y; oa[10] += pv*v2.z; oa[11] += pv*v2.w;
        oa[12] += pv*v3.x; oa[13] += pv*v3.y; oa[14] += pv*v3.z; oa[15] += pv*v3.w;
      }
    }
#pragma unroll
    for (int e = 0; e < 16; ++e) {
#pragma unroll
      for (int d = 1; d < 16; d <<= 1) oa[e] += __shfl_xor(oa[e], d);
    }
    float oc = S[OBS + lane16];
#pragma unroll
    for (int e = 0; e < 16; ++e) oc += oa[e] * inv * S[OWS + e * 16 + lane16];
    float dA = oc * S[AC + lane16];
    float dB = oc * S[BC + lane16];
#pragma unroll
    for (int d = 1; d < 16; d <<= 1) {
      dA += __shfl_xor(dA, d);
      dB += __shfl_xor(dB, d);
    }
    const float g = S[G1L + grp];
    float s0 = 0.f, s1a = 0.f;
#pragma unroll
    for (int cc = 0; cc < 8; ++cc) {
      int u = lane16 + cc * 16;
      if (u < NOFC) {
        float w = S[wavX + u + mi];
        float e1 = __expf(0.25f * g * w);
        s0 += e1; s1a += e1 * w;
      }
    }
#pragma unroll
    for (int d = 1; d < 16; d <<= 1) {
      s0 += __shfl_xor(s0, d);
      s1a += __shfl_xor(s1a, d);
    }
    float h = s1a / s0;
    float dval = h * dA + dB;
    if (lane16 == 0)
      G[G_DD + s * NOFC + t] = sigmf(S[FCW + s] * dval + S[FCB + s]);
  }
  gbar(a.bar + 16);

  // ---- head: out1 rows read G_DD directly; out2 via 2 atomics -----------
  if (grp < 15) {
    int r = wgid * 15 + grp;
    float acc = 0.f;
#pragma unroll
    for (int k = 0; k < 15; ++k) {
      int c = lane16 + 16 * k;
      if (c < 238) acc += S[O1W + grp * 240 + c] * G[G_DD + c];
    }
#pragma unroll
    for (int d = 1; d < 16; d <<= 1) acc += __shfl_xor(acc, d);
    if (lane16 == 0)
      S[HHL + grp] = (r < NOFC) ? sigmf(acc + S[O1B + grp]) : 0.0f;
  }
  __syncthreads();
  if (tid == 0) {
    float p0 = 0.f, p1 = 0.f;
#pragma unroll
    for (int j = 0; j < 15; ++j) {
      p0 += S[O2WS + j] * S[HHL + j];
      p1 += S[O2WS + 15 + j] * S[HHL + j];
    }
    float* acc = (float*)((char*)a.bar + 128);
    unsigned int* done = (unsigned int*)((char*)a.bar + 192);
    __hip_atomic_fetch_add(acc + 0, p0, __ATOMIC_RELAXED, __HIP_MEMORY_SCOPE_AGENT);
    __hip_atomic_fetch_add(acc + 1, p1, __ATOMIC_RELAXED, __HIP_MEMORY_SCOPE_AGENT);
    unsigned old = __hip_atomic_fetch_add(done, 1u, __ATOMIC_ACQ_REL, __HIP_MEMORY_SCOPE_AGENT);
    if (old == NWG - 1) {
      __builtin_amdgcn_fence(__ATOMIC_ACQUIRE, "agent");
      float a0 = __hip_atomic_load(acc + 0, __ATOMIC_RELAXED, __HIP_MEMORY_SCOPE_AGENT);
      float a1 = __hip_atomic_load(acc + 1, __ATOMIC_RELAXED, __HIP_MEMORY_SCOPE_AGENT);
      a.out[0] = sigmf(a0 + S[O2B + 0]);
      a.out[1] = sigmf(a1 + S[O2B + 1]);
    }
  }
}

extern "C" void kernel_launch(void* const* d_in, const int* in_sizes, int n_in,
                              void* d_out, int out_size, void* d_ws, size_t ws_size,
                              hipStream_t stream) {
  Args a;
  a.x        = (const float*)d_in[0];
  a.td_in_w  = (const float*)d_in[1];
  a.td_in_b  = (const float*)d_in[2];
  a.td_out_w = (const float*)d_in[3];
  a.td_out_b = (const float*)d_in[4];
  a.cm_in_w  = (const float*)d_in[5];
  a.cm_in_b  = (const float*)d_in[6];
  a.cm_out_w = (const float*)d_in[7];
  a.cm_out_b = (const float*)d_in[8];
  a.mc_w     = (const float*)d_in[9];
  a.mc_b     = (const float*)d_in[10];
  a.max_fc_w = (const float*)d_in[11];
  a.max_fc_b = (const float*)d_in[12];
  a.proj_w   = (const float*)d_in[13];
  a.ln_g     = (const float*)d_in[14];
  a.ln_b     = (const float*)d_in[15];
  a.fc_w     = (const float*)d_in[16];
  a.fc_b     = (const float*)d_in[17];
  a.out1_w   = (const float*)d_in[18];
  a.out1_b   = (const float*)d_in[19];
  a.out2_w   = (const float*)d_in[20];
  a.out2_b   = (const float*)d_in[21];
  a.out      = (float*)d_out;
  a.bar      = (unsigned int*)d_ws;
  a.G        = (float*)((char*)d_ws + 512);

  // zero barriers + out2 accumulators + done counter each call.
  hipMemsetAsync(d_ws, 0, 512, stream);
  fused_cnn_kernel<<<dim3(NWG), dim3(NT), 0, stream>>>(a);
}